// Round 5
// baseline (175.838 us; speedup 1.0000x reference)
//
#include <hip/hip_runtime.h>
#include <cmath>

namespace {
constexpr int Cc = 256, CKc = 32, CVc = 32, KKc = 9;
constexpr int Bc = 8, Hc = 128, Wc = 128, HWc = Hc * Wc;
}

// ---- Kernel 1: k1 = relu(W_k1 x + b), v = W_v x + b ----
// 256 thr = 4 waves; wave og: 0,1 -> k1 rows [0:16),[16:32); 2,3 -> v rows.
// Each thread: 2 pixels, 16 output rows. Weights staged per-64ch-chunk in LDS.
// Inner loop batches 8 independent global loads to cover HBM latency.
__global__ __launch_bounds__(256) void ns_k1v(
    const float* __restrict__ x,
    const float* __restrict__ k1_w, const float* __restrict__ k1_b,
    const float* __restrict__ v_w,  const float* __restrict__ v_b,
    float* __restrict__ k1, float* __restrict__ v)
{
    __shared__ float ws_t[64][68];              // [ch][oc], padded
    const int tid = threadIdx.x;
    const int q  = tid & 63;
    const int og = __builtin_amdgcn_readfirstlane(tid >> 6);
    const int og16 = og * 16;

    const int flat0 = blockIdx.x * 128;         // 128 px per block
    const int b  = flat0 / HWc;
    const int pb = flat0 - b * HWc;

    const float* xg0 = x + (size_t)b * Cc * HWc + pb + q * 2;

    const int soc = tid >> 2;                   // staging: output row 0..63
    const int sci = tid & 3;

    float2 acc[16];
#pragma unroll
    for (int o = 0; o < 16; ++o) acc[o] = make_float2(0.f, 0.f);

    for (int c0 = 0; c0 < Cc; c0 += 64) {
        __syncthreads();
#pragma unroll
        for (int rep = 0; rep < 4; ++rep) {
            const int ch0 = rep * 16 + sci * 4;
            const float* src = (soc < 32) ? (k1_w + soc * Cc + c0 + ch0)
                                          : (v_w + (soc - 32) * Cc + c0 + ch0);
            const float4 val = *(const float4*)src;
            ws_t[ch0 + 0][soc] = val.x;
            ws_t[ch0 + 1][soc] = val.y;
            ws_t[ch0 + 2][soc] = val.z;
            ws_t[ch0 + 3][soc] = val.w;
        }
        __syncthreads();

        const float* xg = xg0 + (size_t)c0 * HWc;
#pragma unroll 2
        for (int cg = 0; cg < 64; cg += 8) {
            float2 xv[8];
#pragma unroll
            for (int u = 0; u < 8; ++u)
                xv[u] = *(const float2*)(xg + (size_t)(cg + u) * HWc);
#pragma unroll
            for (int u = 0; u < 8; ++u) {
                float wv[16];
                *(float4*)&wv[0]  = *(const float4*)&ws_t[cg + u][og16 + 0];
                *(float4*)&wv[4]  = *(const float4*)&ws_t[cg + u][og16 + 4];
                *(float4*)&wv[8]  = *(const float4*)&ws_t[cg + u][og16 + 8];
                *(float4*)&wv[12] = *(const float4*)&ws_t[cg + u][og16 + 12];
#pragma unroll
                for (int o = 0; o < 16; ++o) {
                    acc[o].x = fmaf(wv[o], xv[u].x, acc[o].x);
                    acc[o].y = fmaf(wv[o], xv[u].y, acc[o].y);
                }
            }
        }
    }

    const bool is_k = og < 2;
    const float* bsrc = is_k ? (k1_b + og16) : (v_b + (og16 - 32));
    float* dst = is_k ? (k1 + ((size_t)b * CKc + og16) * HWc + pb + q * 2)
                      : (v  + ((size_t)b * CVc + (og16 - 32)) * HWc + pb + q * 2);
#pragma unroll
    for (int o = 0; o < 16; ++o) {
        const float bi = bsrc[o];
        float2 r = make_float2(acc[o].x + bi, acc[o].y + bi);
        if (is_k) { r.x = fmaxf(r.x, 0.f); r.y = fmaxf(r.y, 0.f); }
        *(float2*)(dst + (size_t)o * HWc) = r;
    }
}

// -- Kernel 2 (fused): depthwise 3x3 + 1x1 CK->9 + softmax + unfold-aggregate
//    + out conv (CV->C) + bias + residual. 1 px/thread. o_w staged in LDS. --
__global__ __launch_bounds__(256) void ns_fused(
    const float* __restrict__ x,
    const float* __restrict__ k1,
    const float* __restrict__ v,
    const float* __restrict__ dw_w, const float* __restrict__ dw_b,
    const float* __restrict__ k3_w, const float* __restrict__ k3_b,
    const float* __restrict__ o_w,  const float* __restrict__ o_b,
    float* __restrict__ out)
{
    __shared__ float ws[Cc * CVc];              // 32 KiB, o_w layout
    __shared__ float dwt[KKc][CKc];             // transposed depthwise weights
    __shared__ float k3s[KKc][CKc];
    __shared__ float dwbs[CKc];
    __shared__ float k3bs[KKc];
    const int tid = threadIdx.x;
#pragma unroll
    for (int r = 0; r < 8; ++r) {
        const int idx = (r * 256 + tid) * 4;
        *(float4*)&ws[idx] = *(const float4*)&o_w[idx];
    }
    // 288 elements, 256 threads: grid-stride so ALL elements are staged
    for (int idx = tid; idx < CKc * KKc; idx += 256) {
        const int ck = idx / KKc, kk = idx - ck * KKc;
        dwt[kk][ck] = dw_w[idx];
        ((float*)k3s)[idx] = k3_w[idx];
    }
    if (tid < CKc) dwbs[tid] = dw_b[tid];
    if (tid < KKc) k3bs[tid] = k3_b[tid];
    __syncthreads();

    const int gid = blockIdx.x * 256 + tid;
    const int b = gid / HWc;
    const int p = gid - b * HWc;
    const int h = p / Wc;
    const int w = p - h * Wc;

    // ---- depthwise 3x3 on k1 ----
    const float* k1b = k1 + (size_t)b * CKc * HWc;
    float t[CKc];
#pragma unroll
    for (int ck = 0; ck < CKc; ++ck) t[ck] = dwbs[ck];
#pragma unroll
    for (int i = 0; i < 3; ++i) {
        const int hh = h + i - 1;
        if (hh < 0 || hh >= Hc) continue;
#pragma unroll
        for (int j = 0; j < 3; ++j) {
            const int ww = w + j - 1;
            if (ww < 0 || ww >= Wc) continue;
            const int off = hh * Wc + ww;
            const int ij = i * 3 + j;
#pragma unroll
            for (int ck = 0; ck < CKc; ++ck)
                t[ck] = fmaf(k1b[(size_t)ck * HWc + off], dwt[ij][ck], t[ck]);
        }
    }

    // ---- 1x1 CK->9 + softmax ----
    float logit[KKc];
#pragma unroll
    for (int kk = 0; kk < KKc; ++kk) {
        float a = k3bs[kk];
#pragma unroll
        for (int ck = 0; ck < CKc; ++ck)
            a = fmaf(k3s[kk][ck], t[ck], a);
        logit[kk] = a;
    }
    float m = logit[0];
#pragma unroll
    for (int kk = 1; kk < KKc; ++kk) m = fmaxf(m, logit[kk]);
    float s = 0.f;
#pragma unroll
    for (int kk = 0; kk < KKc; ++kk) { logit[kk] = expf(logit[kk] - m); s += logit[kk]; }
    const float inv = 1.f / s;
#pragma unroll
    for (int kk = 0; kk < KKc; ++kk) logit[kk] *= inv;

    // ---- unfold-aggregate: y[cv] in registers ----
    float yv[CVc];
#pragma unroll
    for (int cv = 0; cv < CVc; ++cv) yv[cv] = 0.f;
    const float* vb = v + (size_t)b * CVc * HWc;
#pragma unroll
    for (int i = 0; i < 3; ++i) {
        const int hh = h + i - 1;
        if (hh < 0 || hh >= Hc) continue;
#pragma unroll
        for (int j = 0; j < 3; ++j) {
            const int ww = w + j - 1;
            if (ww < 0 || ww >= Wc) continue;
            const int off = hh * Wc + ww;
            const float wv = logit[i * 3 + j];
#pragma unroll
            for (int cv = 0; cv < CVc; ++cv)
                yv[cv] = fmaf(wv, vb[(size_t)cv * HWc + off], yv[cv]);
        }
    }

    // ---- out conv + residual ----
    const float* xb = x + (size_t)b * Cc * HWc + p;
    float* ob = out + (size_t)b * Cc * HWc + p;
#pragma unroll 4
    for (int o = 0; o < Cc; ++o) {
        float wv[CVc];
#pragma unroll
        for (int r = 0; r < 8; ++r)
            *(float4*)&wv[r * 4] = *(const float4*)&ws[o * CVc + r * 4];
        float acc = o_b[o] + xb[(size_t)o * HWc];
#pragma unroll
        for (int cv = 0; cv < CVc; ++cv)
            acc = fmaf(wv[cv], yv[cv], acc);
        ob[(size_t)o * HWc] = acc;
    }
}

extern "C" void kernel_launch(void* const* d_in, const int* in_sizes, int n_in,
                              void* d_out, int out_size, void* d_ws, size_t ws_size,
                              hipStream_t stream)
{
    const float* x    = (const float*)d_in[0];
    const float* k1_w = (const float*)d_in[1];
    const float* k1_b = (const float*)d_in[2];
    const float* dw_w = (const float*)d_in[3];
    const float* dw_b = (const float*)d_in[4];
    const float* k3_w = (const float*)d_in[5];
    const float* k3_b = (const float*)d_in[6];
    const float* v_w  = (const float*)d_in[7];
    const float* v_b  = (const float*)d_in[8];
    const float* o_w  = (const float*)d_in[9];
    const float* o_b  = (const float*)d_in[10];
    float* out = (float*)d_out;

    // workspace: k1 (16 MiB) | v (16 MiB)
    float* k1 = (float*)d_ws;
    float* v  = k1 + (size_t)Bc * CKc * HWc;

    const int npx = Bc * HWc;                   // 131072

    ns_k1v <<<dim3(npx / 128), dim3(256), 0, stream>>>(x, k1_w, k1_b, v_w, v_b, k1, v);
    ns_fused<<<dim3(npx / 256), dim3(256), 0, stream>>>(x, k1, v, dw_w, dw_b, k3_w, k3_b,
                                                        o_w, o_b, out);
}

// Round 6
// 136.881 us; speedup vs baseline: 1.2846x; 1.2846x over previous
//
#include <hip/hip_runtime.h>
#include <cmath>

namespace {
constexpr int Cc = 256, CKc = 32, CVc = 32, KKc = 9;
constexpr int Bc = 8, Hc = 128, Wc = 128, HWc = Hc * Wc;

typedef __attribute__((ext_vector_type(8))) short   s16x8;
typedef __attribute__((ext_vector_type(8))) __bf16  bf16x8;
typedef __attribute__((ext_vector_type(4))) float   f32x4;

__device__ inline short f2bf(float f) {        // RNE f32 -> bf16 bits
    union { float f; unsigned u; } v; v.f = f;
    unsigned u = v.u + 0x7fffu + ((v.u >> 16) & 1u);
    return (short)(u >> 16);
}
}

// ---- Kernel 1: k1 = relu(W_k1 x + b), v = W_v x + b  (unchanged, verified) ----
__global__ __launch_bounds__(256) void ns_k1v(
    const float* __restrict__ x,
    const float* __restrict__ k1_w, const float* __restrict__ k1_b,
    const float* __restrict__ v_w,  const float* __restrict__ v_b,
    float* __restrict__ k1, float* __restrict__ v)
{
    __shared__ float ws_t[64][68];
    const int tid = threadIdx.x;
    const int q  = tid & 63;
    const int og = __builtin_amdgcn_readfirstlane(tid >> 6);
    const int og16 = og * 16;

    const int flat0 = blockIdx.x * 128;
    const int b  = flat0 / HWc;
    const int pb = flat0 - b * HWc;

    const float* xg0 = x + (size_t)b * Cc * HWc + pb + q * 2;

    const int soc = tid >> 2;
    const int sci = tid & 3;

    float2 acc[16];
#pragma unroll
    for (int o = 0; o < 16; ++o) acc[o] = make_float2(0.f, 0.f);

    for (int c0 = 0; c0 < Cc; c0 += 64) {
        __syncthreads();
#pragma unroll
        for (int rep = 0; rep < 4; ++rep) {
            const int ch0 = rep * 16 + sci * 4;
            const float* src = (soc < 32) ? (k1_w + soc * Cc + c0 + ch0)
                                          : (v_w + (soc - 32) * Cc + c0 + ch0);
            const float4 val = *(const float4*)src;
            ws_t[ch0 + 0][soc] = val.x;
            ws_t[ch0 + 1][soc] = val.y;
            ws_t[ch0 + 2][soc] = val.z;
            ws_t[ch0 + 3][soc] = val.w;
        }
        __syncthreads();

        const float* xg = xg0 + (size_t)c0 * HWc;
#pragma unroll 2
        for (int cg = 0; cg < 64; cg += 8) {
            float2 xv[8];
#pragma unroll
            for (int u = 0; u < 8; ++u)
                xv[u] = *(const float2*)(xg + (size_t)(cg + u) * HWc);
#pragma unroll
            for (int u = 0; u < 8; ++u) {
                float wv[16];
                *(float4*)&wv[0]  = *(const float4*)&ws_t[cg + u][og16 + 0];
                *(float4*)&wv[4]  = *(const float4*)&ws_t[cg + u][og16 + 4];
                *(float4*)&wv[8]  = *(const float4*)&ws_t[cg + u][og16 + 8];
                *(float4*)&wv[12] = *(const float4*)&ws_t[cg + u][og16 + 12];
#pragma unroll
                for (int o = 0; o < 16; ++o) {
                    acc[o].x = fmaf(wv[o], xv[u].x, acc[o].x);
                    acc[o].y = fmaf(wv[o], xv[u].y, acc[o].y);
                }
            }
        }
    }

    const bool is_k = og < 2;
    const float* bsrc = is_k ? (k1_b + og16) : (v_b + (og16 - 32));
    float* dst = is_k ? (k1 + ((size_t)b * CKc + og16) * HWc + pb + q * 2)
                      : (v  + ((size_t)b * CVc + (og16 - 32)) * HWc + pb + q * 2);
#pragma unroll
    for (int o = 0; o < 16; ++o) {
        const float bi = bsrc[o];
        float2 r = make_float2(acc[o].x + bi, acc[o].y + bi);
        if (is_k) { r.x = fmaxf(r.x, 0.f); r.y = fmaxf(r.y, 0.f); }
        *(float2*)(dst + (size_t)o * HWc) = r;
    }
}

// -- Kernel 2 (fused): dw3x3 + 1x1->9 + softmax + unfold-agg (fp32 VALU),
//    then out conv (CV->C) via bf16 MFMA + bias + residual.
//    128 thr (2 waves) per block, 128 px per block (one image row). --
__global__ __launch_bounds__(128) void ns_fused(
    const float* __restrict__ x,
    const float* __restrict__ k1,
    const float* __restrict__ v,
    const float* __restrict__ dw_w, const float* __restrict__ dw_b,
    const float* __restrict__ k3_w, const float* __restrict__ k3_b,
    const float* __restrict__ o_w,  const float* __restrict__ o_b,
    float* __restrict__ out)
{
    constexpr int PX = 128;
    constexpr int WPAD = 40;                    // row stride 80 B: 2-way-free frag reads
    __shared__ short w_lds[Cc][WPAD];           // 20 KiB  o_w as bf16
    __shared__ short y_lds[PX][WPAD];           // 10 KiB  y as bf16
    __shared__ float obs[Cc];                   // 1 KiB
    __shared__ float dwt[KKc][CKc];
    __shared__ float k3s[KKc][CKc];
    __shared__ float dwbs[CKc];
    __shared__ float k3bs[KKc];

    const int tid = threadIdx.x;

    // ---- stage o_w (bf16), o_b, dw/k3 weights ----
#pragma unroll
    for (int r = 0; r < 2; ++r) {
        const int o = tid + r * 128;
        const float* src = o_w + o * CVc;
        alignas(16) short tmp[CVc];
#pragma unroll
        for (int c = 0; c < CVc; c += 4) {
            const float4 f = *(const float4*)(src + c);
            tmp[c+0] = f2bf(f.x); tmp[c+1] = f2bf(f.y);
            tmp[c+2] = f2bf(f.z); tmp[c+3] = f2bf(f.w);
        }
#pragma unroll
        for (int cq = 0; cq < 4; ++cq)
            *(float4*)&w_lds[o][cq * 8] = *(const float4*)&tmp[cq * 8];
        obs[o] = o_b[o];
    }
    for (int idx = tid; idx < CKc * KKc; idx += 128) {
        const int ck = idx / KKc, kk = idx - ck * KKc;
        dwt[kk][ck] = dw_w[idx];
        ((float*)k3s)[idx] = k3_w[idx];
    }
    if (tid < CKc) dwbs[tid] = dw_b[tid];
    if (tid < KKc) k3bs[tid] = k3_b[tid];
    __syncthreads();

    // ---- phase 1: per-pixel y[32] ----
    const int flat0 = blockIdx.x * PX;
    const int b  = flat0 / HWc;
    const int p0 = flat0 - b * HWc;
    const int p  = p0 + tid;
    const int h  = p / Wc;
    const int w  = p - h * Wc;

    const float* k1b = k1 + (size_t)b * CKc * HWc;
    float t[CKc];
#pragma unroll
    for (int ck = 0; ck < CKc; ++ck) t[ck] = dwbs[ck];
#pragma unroll
    for (int i = 0; i < 3; ++i) {
        const int hh = h + i - 1;
        if (hh < 0 || hh >= Hc) continue;
#pragma unroll
        for (int j = 0; j < 3; ++j) {
            const int ww = w + j - 1;
            if (ww < 0 || ww >= Wc) continue;
            const int off = hh * Wc + ww;
            const int ij = i * 3 + j;
#pragma unroll
            for (int ck = 0; ck < CKc; ++ck)
                t[ck] = fmaf(k1b[(size_t)ck * HWc + off], dwt[ij][ck], t[ck]);
        }
    }

    float logit[KKc];
#pragma unroll
    for (int kk = 0; kk < KKc; ++kk) {
        float a = k3bs[kk];
#pragma unroll
        for (int ck = 0; ck < CKc; ++ck)
            a = fmaf(k3s[kk][ck], t[ck], a);
        logit[kk] = a;
    }
    float m = logit[0];
#pragma unroll
    for (int kk = 1; kk < KKc; ++kk) m = fmaxf(m, logit[kk]);
    float s = 0.f;
#pragma unroll
    for (int kk = 0; kk < KKc; ++kk) { logit[kk] = expf(logit[kk] - m); s += logit[kk]; }
    const float inv = 1.f / s;
#pragma unroll
    for (int kk = 0; kk < KKc; ++kk) logit[kk] *= inv;

    float yv[CVc];
#pragma unroll
    for (int cv = 0; cv < CVc; ++cv) yv[cv] = 0.f;
    const float* vb = v + (size_t)b * CVc * HWc;
#pragma unroll
    for (int i = 0; i < 3; ++i) {
        const int hh = h + i - 1;
        if (hh < 0 || hh >= Hc) continue;
#pragma unroll
        for (int j = 0; j < 3; ++j) {
            const int ww = w + j - 1;
            if (ww < 0 || ww >= Wc) continue;
            const int off = hh * Wc + ww;
            const float wv = logit[i * 3 + j];
#pragma unroll
            for (int cv = 0; cv < CVc; ++cv)
                yv[cv] = fmaf(wv, vb[(size_t)cv * HWc + off], yv[cv]);
        }
    }

    // write y to LDS as bf16 [px][cv]
    {
        alignas(16) short ybf[CVc];
#pragma unroll
        for (int cv = 0; cv < CVc; ++cv) ybf[cv] = f2bf(yv[cv]);
#pragma unroll
        for (int cq = 0; cq < 4; ++cq)
            *(float4*)&y_lds[tid][cq * 8] = *(const float4*)&ybf[cq * 8];
    }
    __syncthreads();

    // ---- phase 2: out[o][px] = x + sum_cv w[o][cv] y[cv][px] + b  via MFMA ----
    const int wv = tid >> 6;                    // wave 0..1 -> o-tiles [wv*8, wv*8+8)
    const int l  = tid & 63;
    const int li = l & 15;                      // D col = px within tile; A row = o
    const int lk = l >> 4;                      // k-group; D rows (lk*4 + r)

    const float* xb0 = x + (size_t)b * Cc * HWc;
    float* ob0 = out + (size_t)b * Cc * HWc;

    for (int ot = wv * 8; ot < wv * 8 + 8; ++ot) {
        const s16x8 araw = *(const s16x8*)&w_lds[ot * 16 + li][lk * 8];
        const bf16x8 afrag = __builtin_bit_cast(bf16x8, araw);
        const int obase = ot * 16 + lk * 4;
        const f32x4 bias = *(const f32x4*)&obs[obase];
#pragma unroll
        for (int pt = 0; pt < 8; ++pt) {
            const s16x8 braw = *(const s16x8*)&y_lds[pt * 16 + li][lk * 8];
            const bf16x8 bfrag = __builtin_bit_cast(bf16x8, braw);
            f32x4 acc = {0.f, 0.f, 0.f, 0.f};
            acc = __builtin_amdgcn_mfma_f32_16x16x32_bf16(afrag, bfrag, acc, 0, 0, 0);
            const int px = p0 + pt * 16 + li;
            const float* xp = xb0 + (size_t)obase * HWc + px;
            float* op = ob0 + (size_t)obase * HWc + px;
#pragma unroll
            for (int r = 0; r < 4; ++r)
                op[(size_t)r * HWc] = xp[(size_t)r * HWc] + acc[r] + bias[r];
        }
    }
}

extern "C" void kernel_launch(void* const* d_in, const int* in_sizes, int n_in,
                              void* d_out, int out_size, void* d_ws, size_t ws_size,
                              hipStream_t stream)
{
    const float* x    = (const float*)d_in[0];
    const float* k1_w = (const float*)d_in[1];
    const float* k1_b = (const float*)d_in[2];
    const float* dw_w = (const float*)d_in[3];
    const float* dw_b = (const float*)d_in[4];
    const float* k3_w = (const float*)d_in[5];
    const float* k3_b = (const float*)d_in[6];
    const float* v_w  = (const float*)d_in[7];
    const float* v_b  = (const float*)d_in[8];
    const float* o_w  = (const float*)d_in[9];
    const float* o_b  = (const float*)d_in[10];
    float* out = (float*)d_out;

    float* k1 = (float*)d_ws;
    float* v  = k1 + (size_t)Bc * CKc * HWc;

    const int npx = Bc * HWc;                   // 131072

    ns_k1v <<<dim3(npx / 128), dim3(256), 0, stream>>>(x, k1_w, k1_b, v_w, v_b, k1, v);
    ns_fused<<<dim3(npx / 128), dim3(128), 0, stream>>>(x, k1, v, dw_w, dw_b, k3_w, k3_b,
                                                        o_w, o_b, out);
}

// Round 7
// 102.349 us; speedup vs baseline: 1.7180x; 1.3374x over previous
//
#include <hip/hip_runtime.h>
#include <cmath>

namespace {
constexpr int Cc = 256, CKc = 32, CVc = 32, KKc = 9;
constexpr int Bc = 8, Hc = 128, Wc = 128, HWc = Hc * Wc;

typedef __attribute__((ext_vector_type(8))) short   s16x8;
typedef __attribute__((ext_vector_type(8))) __bf16  bf16x8;
typedef __attribute__((ext_vector_type(4))) float   f32x4;

__device__ inline short f2bf(float f) {        // RNE f32 -> bf16 bits
    union { float f; unsigned u; } v; v.f = f;
    unsigned u = v.u + 0x7fffu + ((v.u >> 16) & 1u);
    return (short)(u >> 16);
}
}

// ---- Kernel 1: k1 = relu(W_k1 x + b), v = W_v x + b  via bf16 MFMA ----
// Block: 256 thr (4 waves) x 128 px, K=256 in 4 chunks of 64.
// Wave wv owns o-tile [wv*16, wv*16+16): wv 0,1 -> k1 rows; wv 2,3 -> v rows.
__global__ __launch_bounds__(256) void ns_k1v(
    const float* __restrict__ x,
    const float* __restrict__ k1_w, const float* __restrict__ k1_b,
    const float* __restrict__ v_w,  const float* __restrict__ v_b,
    float* __restrict__ k1, float* __restrict__ v)
{
    constexpr int LP = 72;                      // row stride (shorts): 144 B, 16B-aligned
    __shared__ short w_bf[64][LP];              // 9.2 KB  chunk of W (64 o x 64 ch)
    __shared__ short x_bf[128][LP];             // 18.4 KB chunk of X (128 px x 64 ch)

    const int tid = threadIdx.x;
    const int l   = tid & 63;
    const int li  = l & 15;
    const int lk  = l >> 4;
    const int wv  = __builtin_amdgcn_readfirstlane(tid >> 6);

    const int flat0 = blockIdx.x * 128;
    const int b  = flat0 / HWc;
    const int pp = flat0 - b * HWc;
    const float* xb = x + (size_t)b * Cc * HWc + pp;

    // staging roles
    const int spx  = tid & 127;                 // X: pixel row (0..127)
    const int schh = tid >> 7;                  // X: ch-quad half (0/1)
    const int so   = tid & 63;                  // W: output row (0..63)
    const int swc0 = (tid >> 6) * 16;           // W: ch base within chunk
    const float* wsrc = (so < 32) ? (k1_w + (size_t)so * Cc)
                                  : (v_w + (size_t)(so - 32) * Cc);

    f32x4 acc[8];
    const f32x4 zero = {0.f, 0.f, 0.f, 0.f};
#pragma unroll
    for (int i = 0; i < 8; ++i) acc[i] = zero;

    for (int c0 = 0; c0 < Cc; c0 += 64) {
        __syncthreads();                        // guard LDS reuse vs prev chunk reads
        // ---- stage W chunk: thread loads 16 ch of its output row ----
        {
            alignas(16) short tmp[16];
#pragma unroll
            for (int f = 0; f < 4; ++f) {
                const float4 fv = *(const float4*)(wsrc + c0 + swc0 + f * 4);
                tmp[f*4+0] = f2bf(fv.x); tmp[f*4+1] = f2bf(fv.y);
                tmp[f*4+2] = f2bf(fv.z); tmp[f*4+3] = f2bf(fv.w);
            }
            *(s16x8*)&w_bf[so][swc0]     = *(const s16x8*)&tmp[0];
            *(s16x8*)&w_bf[so][swc0 + 8] = *(const s16x8*)&tmp[8];
        }
        // ---- stage X chunk: thread owns px=spx, 8 ch-quads (px-coalesced loads) ----
#pragma unroll
        for (int u = 0; u < 8; ++u) {
            const int ch = (schh * 8 + u) * 4;
            const float e0 = xb[(size_t)(c0 + ch + 0) * HWc + spx];
            const float e1 = xb[(size_t)(c0 + ch + 1) * HWc + spx];
            const float e2 = xb[(size_t)(c0 + ch + 2) * HWc + spx];
            const float e3 = xb[(size_t)(c0 + ch + 3) * HWc + spx];
            const unsigned p01 = (unsigned)(unsigned short)f2bf(e0)
                               | ((unsigned)(unsigned short)f2bf(e1) << 16);
            const unsigned p23 = (unsigned)(unsigned short)f2bf(e2)
                               | ((unsigned)(unsigned short)f2bf(e3) << 16);
            *(uint2*)&x_bf[spx][ch] = make_uint2(p01, p23);
        }
        __syncthreads();

        // ---- compute: 2 K-steps x 8 px-tiles of 16x16x32 MFMA ----
#pragma unroll
        for (int ks = 0; ks < 2; ++ks) {
            const s16x8 ar = *(const s16x8*)&w_bf[wv * 16 + li][ks * 32 + lk * 8];
            const bf16x8 af = __builtin_bit_cast(bf16x8, ar);
#pragma unroll
            for (int pt = 0; pt < 8; ++pt) {
                const s16x8 br = *(const s16x8*)&x_bf[pt * 16 + li][ks * 32 + lk * 8];
                acc[pt] = __builtin_amdgcn_mfma_f32_16x16x32_bf16(
                    af, __builtin_bit_cast(bf16x8, br), acc[pt], 0, 0, 0);
            }
        }
    }

    // ---- epilogue: bias (+relu for k1), f32 store ----
    const bool is_k = wv < 2;
    const int obase = wv * 16 + lk * 4;         // +r
    float bias[4];
#pragma unroll
    for (int r = 0; r < 4; ++r)
        bias[r] = is_k ? k1_b[obase + r] : v_b[obase + r - 32];
    float* dst0 = is_k ? (k1 + ((size_t)b * CKc + obase) * HWc + pp)
                       : (v  + ((size_t)b * CVc + (obase - 32)) * HWc + pp);
#pragma unroll
    for (int pt = 0; pt < 8; ++pt) {
        const int px = pt * 16 + li;
#pragma unroll
        for (int r = 0; r < 4; ++r) {
            float val = acc[pt][r] + bias[r];
            if (is_k) val = fmaxf(val, 0.f);
            dst0[(size_t)r * HWc + px] = val;
        }
    }
}

// -- Kernel 2 (fused): dw3x3 + 1x1->9 + softmax + unfold-agg (fp32 VALU),
//    then out conv (CV->C) via bf16 MFMA + bias + residual. UNCHANGED from R6. --
__global__ __launch_bounds__(128) void ns_fused(
    const float* __restrict__ x,
    const float* __restrict__ k1,
    const float* __restrict__ v,
    const float* __restrict__ dw_w, const float* __restrict__ dw_b,
    const float* __restrict__ k3_w, const float* __restrict__ k3_b,
    const float* __restrict__ o_w,  const float* __restrict__ o_b,
    float* __restrict__ out)
{
    constexpr int PX = 128;
    constexpr int WPAD = 40;
    __shared__ short w_lds[Cc][WPAD];
    __shared__ short y_lds[PX][WPAD];
    __shared__ float obs[Cc];
    __shared__ float dwt[KKc][CKc];
    __shared__ float k3s[KKc][CKc];
    __shared__ float dwbs[CKc];
    __shared__ float k3bs[KKc];

    const int tid = threadIdx.x;

#pragma unroll
    for (int r = 0; r < 2; ++r) {
        const int o = tid + r * 128;
        const float* src = o_w + o * CVc;
        alignas(16) short tmp[CVc];
#pragma unroll
        for (int c = 0; c < CVc; c += 4) {
            const float4 f = *(const float4*)(src + c);
            tmp[c+0] = f2bf(f.x); tmp[c+1] = f2bf(f.y);
            tmp[c+2] = f2bf(f.z); tmp[c+3] = f2bf(f.w);
        }
#pragma unroll
        for (int cq = 0; cq < 4; ++cq)
            *(float4*)&w_lds[o][cq * 8] = *(const float4*)&tmp[cq * 8];
        obs[o] = o_b[o];
    }
    for (int idx = tid; idx < CKc * KKc; idx += 128) {
        const int ck = idx / KKc, kk = idx - ck * KKc;
        dwt[kk][ck] = dw_w[idx];
        ((float*)k3s)[idx] = k3_w[idx];
    }
    if (tid < CKc) dwbs[tid] = dw_b[tid];
    if (tid < KKc) k3bs[tid] = k3_b[tid];
    __syncthreads();

    const int flat0 = blockIdx.x * PX;
    const int b  = flat0 / HWc;
    const int p0 = flat0 - b * HWc;
    const int p  = p0 + tid;
    const int h  = p / Wc;
    const int w  = p - h * Wc;

    const float* k1b = k1 + (size_t)b * CKc * HWc;
    float t[CKc];
#pragma unroll
    for (int ck = 0; ck < CKc; ++ck) t[ck] = dwbs[ck];
#pragma unroll
    for (int i = 0; i < 3; ++i) {
        const int hh = h + i - 1;
        if (hh < 0 || hh >= Hc) continue;
#pragma unroll
        for (int j = 0; j < 3; ++j) {
            const int ww = w + j - 1;
            if (ww < 0 || ww >= Wc) continue;
            const int off = hh * Wc + ww;
            const int ij = i * 3 + j;
#pragma unroll
            for (int ck = 0; ck < CKc; ++ck)
                t[ck] = fmaf(k1b[(size_t)ck * HWc + off], dwt[ij][ck], t[ck]);
        }
    }

    float logit[KKc];
#pragma unroll
    for (int kk = 0; kk < KKc; ++kk) {
        float a = k3bs[kk];
#pragma unroll
        for (int ck = 0; ck < CKc; ++ck)
            a = fmaf(k3s[kk][ck], t[ck], a);
        logit[kk] = a;
    }
    float m = logit[0];
#pragma unroll
    for (int kk = 1; kk < KKc; ++kk) m = fmaxf(m, logit[kk]);
    float s = 0.f;
#pragma unroll
    for (int kk = 0; kk < KKc; ++kk) { logit[kk] = expf(logit[kk] - m); s += logit[kk]; }
    const float inv = 1.f / s;
#pragma unroll
    for (int kk = 0; kk < KKc; ++kk) logit[kk] *= inv;

    float yv[CVc];
#pragma unroll
    for (int cv = 0; cv < CVc; ++cv) yv[cv] = 0.f;
    const float* vb = v + (size_t)b * CVc * HWc;
#pragma unroll
    for (int i = 0; i < 3; ++i) {
        const int hh = h + i - 1;
        if (hh < 0 || hh >= Hc) continue;
#pragma unroll
        for (int j = 0; j < 3; ++j) {
            const int ww = w + j - 1;
            if (ww < 0 || ww >= Wc) continue;
            const int off = hh * Wc + ww;
            const float wv = logit[i * 3 + j];
#pragma unroll
            for (int cv = 0; cv < CVc; ++cv)
                yv[cv] = fmaf(wv, vb[(size_t)cv * HWc + off], yv[cv]);
        }
    }

    {
        alignas(16) short ybf[CVc];
#pragma unroll
        for (int cv = 0; cv < CVc; ++cv) ybf[cv] = f2bf(yv[cv]);
#pragma unroll
        for (int cq = 0; cq < 4; ++cq)
            *(float4*)&y_lds[tid][cq * 8] = *(const float4*)&ybf[cq * 8];
    }
    __syncthreads();

    const int wvv = tid >> 6;
    const int l  = tid & 63;
    const int li = l & 15;
    const int lk = l >> 4;

    const float* xb0 = x + (size_t)b * Cc * HWc;
    float* ob0 = out + (size_t)b * Cc * HWc;

    for (int ot = wvv * 8; ot < wvv * 8 + 8; ++ot) {
        const s16x8 araw = *(const s16x8*)&w_lds[ot * 16 + li][lk * 8];
        const bf16x8 afrag = __builtin_bit_cast(bf16x8, araw);
        const int obase = ot * 16 + lk * 4;
        const f32x4 bias = *(const f32x4*)&obs[obase];
#pragma unroll
        for (int pt = 0; pt < 8; ++pt) {
            const s16x8 braw = *(const s16x8*)&y_lds[pt * 16 + li][lk * 8];
            const bf16x8 bfrag = __builtin_bit_cast(bf16x8, braw);
            f32x4 acc = {0.f, 0.f, 0.f, 0.f};
            acc = __builtin_amdgcn_mfma_f32_16x16x32_bf16(afrag, bfrag, acc, 0, 0, 0);
            const int px = p0 + pt * 16 + li;
            const float* xp = xb0 + (size_t)obase * HWc + px;
            float* op = ob0 + (size_t)obase * HWc + px;
#pragma unroll
            for (int r = 0; r < 4; ++r)
                op[(size_t)r * HWc] = xp[(size_t)r * HWc] + acc[r] + bias[r];
        }
    }
}

extern "C" void kernel_launch(void* const* d_in, const int* in_sizes, int n_in,
                              void* d_out, int out_size, void* d_ws, size_t ws_size,
                              hipStream_t stream)
{
    const float* x    = (const float*)d_in[0];
    const float* k1_w = (const float*)d_in[1];
    const float* k1_b = (const float*)d_in[2];
    const float* dw_w = (const float*)d_in[3];
    const float* dw_b = (const float*)d_in[4];
    const float* k3_w = (const float*)d_in[5];
    const float* k3_b = (const float*)d_in[6];
    const float* v_w  = (const float*)d_in[7];
    const float* v_b  = (const float*)d_in[8];
    const float* o_w  = (const float*)d_in[9];
    const float* o_b  = (const float*)d_in[10];
    float* out = (float*)d_out;

    float* k1 = (float*)d_ws;
    float* v  = k1 + (size_t)Bc * CKc * HWc;

    const int npx = Bc * HWc;                   // 131072

    ns_k1v <<<dim3(npx / 128), dim3(256), 0, stream>>>(x, k1_w, k1_b, v_w, v_b, k1, v);
    ns_fused<<<dim3(npx / 128), dim3(128), 0, stream>>>(x, k1, v, dw_w, dw_b, k3_w, k3_b,
                                                        o_w, o_b, out);
}